// Round 18
// baseline (70.817 us; speedup 1.0000x reference)
//
#include <hip/hip_runtime.h>
#include <hip/hip_cooperative_groups.h>
#include <math.h>

namespace cg = cooperative_groups;

#define NB 32
#define NN 10000
#define DIM 256
#define NH 16
#define NPART 16          // 32*16 = 512 blocks = 2/CU target
#define PREC2 4112        // per-block partial: l[16] + g[16*256]
#define IDXSTRIDE 10240

typedef short short8v __attribute__((ext_vector_type(8)));
typedef float float4v __attribute__((ext_vector_type(4)));

// ---- bf16 helpers (RNE pack) ----
__device__ __forceinline__ unsigned bf16rne(float f) {
    unsigned u = __float_as_uint(f);
    return (u + 0x7FFFu + ((u >> 16) & 1u)) >> 16;
}
__device__ __forceinline__ unsigned pack2(float a, float b) {
    return bf16rne(a) | (bf16rne(b) << 16);
}
__device__ __forceinline__ short8v pack8(float4 A, float4 B) {
    union { short8v s; unsigned u[4]; } r;
    r.u[0] = pack2(A.x, A.y); r.u[1] = pack2(A.z, A.w);
    r.u[2] = pack2(B.x, B.y); r.u[3] = pack2(B.z, B.w);
    return r.s;
}
// row-parity XOR swizzle for XT (128B rows)
#define SWB(d) ((((d) >> 1) & 7) << 4)

// Raw barrier: waits LDS ops only, does NOT drain vmcnt.
__device__ __forceinline__ void barrier_keep_vmcnt() {
    __builtin_amdgcn_sched_barrier(0);
    asm volatile("s_waitcnt lgkmcnt(0)");
    __builtin_amdgcn_s_barrier();
    __builtin_amdgcn_sched_barrier(0);
}

// ---- shared macro pieces (expand at use site) ----
#define XTBUF(bb) (smem + (size_t)(bb) * 32768)
#define PLBUF(bb) (smem + 65536 + (size_t)(bb) * 2304)

#define STEP_A(cc) { \
    short8v af = pack8(LA##cc, LB##cc); \
    union { short8v s; unsigned short u[8]; } U; U.s = af; \
    int d0 = g * 8 + cc * 32; \
    _Pragma("unroll") \
    for (int j = 0; j < 8; ++j) \
        *(unsigned short*)(XTc + (size_t)(d0 + j) * 128 + \
                           (ln2 ^ SWB(d0 + j))) = U.u[j]; \
    acc = __builtin_amdgcn_mfma_f32_16x16x32_bf16(af, wfrag##cc, acc, 0, 0, 0); \
}

#define PHASE_A_TAIL(tb_, cur_) { \
    char* XTc = XTBUF(cur_); char* PLc = PLBUF(cur_); \
    float4v acc = (float4v){0.f, 0.f, 0.f, 0.f}; \
    STEP_A(0) STEP_A(1) STEP_A(2) STEP_A(3) \
    STEP_A(4) STEP_A(5) STEP_A(6) STEP_A(7) \
    int mb_ = (tb_) + 16 * w + 4 * g; \
    float p0 = (mb_ + 0 < n1) ? __expf(acc[0]) : 0.f; \
    float p1 = (mb_ + 1 < n1) ? __expf(acc[1]) : 0.f; \
    float p2 = (mb_ + 2 < n1) ? __expf(acc[2]) : 0.f; \
    float p3 = (mb_ + 3 < n1) ? __expf(acc[3]) : 0.f; \
    float ts = p0 + p1 + p2 + p3; \
    ts += __shfl_xor(ts, 16, 64); \
    ts += __shfl_xor(ts, 32, 64); \
    lacc += ts; \
    *(uint2*)(PLc + hq * 144 + (16 * w + 4 * g) * 2) = \
        make_uint2(pack2(p0, p1), pack2(p2, p3)); \
}

#define PHASE_B(bb) { \
    char* XTp = XTBUF(bb); char* PLp = PLBUF(bb); \
    _Pragma("unroll") \
    for (int chunk = 0; chunk < 2; ++chunk) { \
        short8v pf = *(const short8v*)(PLp + hq * 144 + chunk * 64 + g * 16); \
        int d0 = 64 * w + hq; \
        short8v xf0 = *(const short8v*)(XTp + (size_t)(d0) * 128 + \
                                        ((chunk * 64 + g * 16) ^ SWB(d0))); \
        short8v xf1 = *(const short8v*)(XTp + (size_t)(d0 + 16) * 128 + \
                                        ((chunk * 64 + g * 16) ^ SWB(d0 + 16))); \
        short8v xf2 = *(const short8v*)(XTp + (size_t)(d0 + 32) * 128 + \
                                        ((chunk * 64 + g * 16) ^ SWB(d0 + 32))); \
        short8v xf3 = *(const short8v*)(XTp + (size_t)(d0 + 48) * 128 + \
                                        ((chunk * 64 + g * 16) ^ SWB(d0 + 48))); \
        accB0 = __builtin_amdgcn_mfma_f32_16x16x32_bf16(xf0, pf, accB0, 0, 0, 0); \
        accB1 = __builtin_amdgcn_mfma_f32_16x16x32_bf16(xf1, pf, accB1, 0, 0, 0); \
        accB2 = __builtin_amdgcn_mfma_f32_16x16x32_bf16(xf2, pf, accB2, 0, 0, 0); \
        accB3 = __builtin_amdgcn_mfma_f32_16x16x32_bf16(xf3, pf, accB3, 0, 0, 0); \
    } \
}

#define LOAD_TILE(nextpos_) { \
    const float* arow = nb + (size_t)ni * DIM + g * 8; \
    LA0 = *(const float4*)(arow + 0);   LB0 = *(const float4*)(arow + 4); \
    LA1 = *(const float4*)(arow + 32);  LB1 = *(const float4*)(arow + 36); \
    LA2 = *(const float4*)(arow + 64);  LB2 = *(const float4*)(arow + 68); \
    LA3 = *(const float4*)(arow + 96);  LB3 = *(const float4*)(arow + 100); \
    LA4 = *(const float4*)(arow + 128); LB4 = *(const float4*)(arow + 132); \
    LA5 = *(const float4*)(arow + 160); LB5 = *(const float4*)(arow + 164); \
    LA6 = *(const float4*)(arow + 192); LB6 = *(const float4*)(arow + 196); \
    LA7 = *(const float4*)(arow + 224); LB7 = *(const float4*)(arow + 228); \
    ni = ib[nextpos_]; \
    __builtin_amdgcn_sched_group_barrier(0x20, 17, 0); \
}

#define CLAMPPOS(base_) ((base_) + 16 * w + hq > cnt - 1 ? cnt - 1 : (base_) + 16 * w + hq)

// ==== attend body (shared between mega phase-2 and standalone kernel) =======
#define ATTEND_BODY(bid_) { \
    float* LL = (float*)(smem + 70144); \
    int b = (bid_) / NPART; \
    int part = (bid_) % NPART; \
    int w = __builtin_amdgcn_readfirstlane(t >> 6); \
    int hq = lane & 15, g = lane >> 4; \
    int cnt = cntp[b]; \
    int psz = ((cnt + NPART * 64 - 1) / (NPART * 64)) * 64; \
    int n0 = part * psz; \
    int n1 = n0 + psz; if (n1 > cnt) n1 = cnt; \
    const float* nb = node + (size_t)b * NN * DIM; \
    const int* ib = idx + (size_t)b * IDXSTRIDE; \
    short8v wfrag0, wfrag1, wfrag2, wfrag3, wfrag4, wfrag5, wfrag6, wfrag7; \
    { \
        const float* wrow = wt + ((size_t)b * NH + hq) * DIM + g * 8; \
        wfrag0 = pack8(*(const float4*)(wrow + 0),   *(const float4*)(wrow + 4)); \
        wfrag1 = pack8(*(const float4*)(wrow + 32),  *(const float4*)(wrow + 36)); \
        wfrag2 = pack8(*(const float4*)(wrow + 64),  *(const float4*)(wrow + 68)); \
        wfrag3 = pack8(*(const float4*)(wrow + 96),  *(const float4*)(wrow + 100)); \
        wfrag4 = pack8(*(const float4*)(wrow + 128), *(const float4*)(wrow + 132)); \
        wfrag5 = pack8(*(const float4*)(wrow + 160), *(const float4*)(wrow + 164)); \
        wfrag6 = pack8(*(const float4*)(wrow + 192), *(const float4*)(wrow + 196)); \
        wfrag7 = pack8(*(const float4*)(wrow + 224), *(const float4*)(wrow + 228)); \
    } \
    float4v accB0 = (float4v){0.f,0.f,0.f,0.f}; \
    float4v accB1 = accB0, accB2 = accB0, accB3 = accB0; \
    float lacc = 0.f; \
    int ln2 = (16 * w + hq) * 2; \
    float4 LA0, LA1, LA2, LA3, LA4, LA5, LA6, LA7; \
    float4 LB0, LB1, LB2, LB3, LB4, LB5, LB6, LB7; \
    int ni; \
    if (n0 < n1) { \
        int nt = (n1 - n0 + 63) >> 6; \
        ni = ib[CLAMPPOS(n0)]; \
        LOAD_TILE(CLAMPPOS(n0 + 64)) \
        PHASE_A_TAIL(n0, 0) \
        if (nt > 1) { \
            LOAD_TILE(CLAMPPOS(n0 + 128)) \
        } \
        barrier_keep_vmcnt(); \
        for (int tb = n0 + 64; tb < n1; tb += 64) { \
            int k = (tb - n0) >> 6; \
            int cur = k & 1; \
            PHASE_B(cur ^ 1) \
            PHASE_A_TAIL(tb, cur) \
            if (tb + 64 < n1) { \
                LOAD_TILE(CLAMPPOS(tb + 128)) \
            } \
            barrier_keep_vmcnt(); \
        } \
        PHASE_B((nt - 1) & 1) \
    } \
    __syncthreads(); \
    float* GL = (float*)smem; \
    _Pragma("unroll") \
    for (int r = 0; r < 4; ++r) { \
        GL[hq * 260 + 64 * w +  0 + 4 * g + r] = accB0[r]; \
        GL[hq * 260 + 64 * w + 16 + 4 * g + r] = accB1[r]; \
        GL[hq * 260 + 64 * w + 32 + 4 * g + r] = accB2[r]; \
        GL[hq * 260 + 64 * w + 48 + 4 * g + r] = accB3[r]; \
    } \
    if (lane < 16) LL[w * 16 + lane] = lacc; \
    __syncthreads(); \
    float* rec = partials + (size_t)(bid_) * PREC2; \
    if (t < NH) rec[t] = LL[t] + LL[16 + t] + LL[32 + t] + LL[48 + t]; \
    for (int i = t; i < NH * DIM; i += 256) \
        rec[16 + i] = GL[(i >> 8) * 260 + (i & 255)]; \
}

// ==== prep body (one block of the prep grid) ================================
#define PREP_BODY(bid_) { \
    int w = t >> 6; \
    int b = (bid_) >> 2, iq = (bid_) & 3; \
    float* ctxL = (float*)smem; \
    float* qL = (float*)(smem + 1024); \
    ctxL[t] = ctx[b * DIM + t]; \
    __syncthreads(); \
    float4 c = ((const float4*)ctxL)[lane]; \
    for (int i = iq * 64 + w; i < iq * 64 + 64; i += 4) { \
        float4 wq = ((const float4*)(Wq + (size_t)i * DIM))[lane]; \
        float s = wq.x * c.x + wq.y * c.y + wq.z * c.z + wq.w * c.w; \
        _Pragma("unroll") \
        for (int off = 1; off < 64; off <<= 1) s += __shfl_xor(s, off, 64); \
        if (lane == 0) qL[i - iq * 64] = s; \
    } \
    __syncthreads(); \
    _Pragma("unroll") \
    for (int hh = 0; hh < 4; ++hh) { \
        int h = iq * 4 + hh; \
        float a = 0.f; \
        _Pragma("unroll") \
        for (int j = 0; j < 16; ++j) \
            a += qL[hh * 16 + j] * Wk[(size_t)(h * 16 + j) * DIM + t]; \
        wt[((size_t)b * NH + h) * DIM + t] = 0.25f * a; \
    } \
}

// ==== compact body ==========================================================
#define COMPACT_BODY(b_) { \
    int w = t >> 6; \
    int b = (b_); \
    int* sflag = (int*)smem; \
    int* wcnt = (int*)(smem + 16); \
    const int* wordbase = (const int*)maskp + (size_t)b * (NN / 4); \
    int bad = 0; \
    for (int i = t; i < NN / 4; i += 256) \
        if ((unsigned)wordbase[i] > 1u) bad = 1; \
    if (t == 0) *sflag = 0; \
    __syncthreads(); \
    if (bad) *sflag = 1; \
    __syncthreads(); \
    const bool bytemask = (*sflag != 0); \
    const unsigned char* m8 = (const unsigned char*)maskp + (size_t)b * NN; \
    const int* m32 = (const int*)maskp + (size_t)b * NN; \
    int segbeg = w * (NN / 4); \
    int segend = segbeg + (NN / 4); \
    int c1 = 0; \
    for (int base = segbeg; base < segend; base += 64) { \
        int i = base + lane; \
        int pred = (i < segend) ? (bytemask ? (m8[i] != 0) : (m32[i] != 0)) : 0; \
        unsigned long long bal = __ballot(pred); \
        c1 += __popcll(bal); \
    } \
    if (lane == 0) wcnt[w] = c1; \
    __syncthreads(); \
    int run = 0; \
    for (int k = 0; k < w; ++k) run += wcnt[k]; \
    int* ob = idx + (size_t)b * IDXSTRIDE; \
    for (int base = segbeg; base < segend; base += 64) { \
        int i = base + lane; \
        int pred = (i < segend) ? (bytemask ? (m8[i] != 0) : (m32[i] != 0)) : 0; \
        unsigned long long bal = __ballot(pred); \
        int rank = __popcll(bal & ((1ull << lane) - 1ull)); \
        if (pred) ob[run + rank] = i; \
        run += __popcll(bal); \
    } \
    if (t == 0) cntp[b] = wcnt[0] + wcnt[1] + wcnt[2] + wcnt[3]; \
}

// ---------------- cooperative mega-kernel -----------------------------------
__global__ void __launch_bounds__(256, 2)
mega_kernel(const float* __restrict__ ctx, const float* __restrict__ node,
            const void* __restrict__ maskp,
            const float* __restrict__ Wq, const float* __restrict__ Wk,
            const float* __restrict__ Wv, const float* __restrict__ Wo,
            float* __restrict__ wt, int* __restrict__ idx,
            int* __restrict__ cntp, float* __restrict__ partials,
            float* __restrict__ hcws, float* __restrict__ out) {
    __shared__ __align__(16) char smem[70400];
    cg::grid_group grid = cg::this_grid();
    int bid = blockIdx.x;
    int t = threadIdx.x, lane = t & 63;

    if (bid < 4 * NB) {
        PREP_BODY(bid)
    } else if (bid < 5 * NB) {
        COMPACT_BODY(bid - 4 * NB)
    }
    __threadfence();
    grid.sync();

    ATTEND_BODY(bid)
    __threadfence();
    grid.sync();

    {   // reduce + hc: block (b,h)
        int b = bid >> 4, h = bid & 15;
        float* grow = (float*)smem;
        float* lp = (float*)(smem + 1024);
        float* lsum = (float*)(smem + 1088);
        const float* pb = partials + (size_t)b * NPART * PREC2;
        float a = 0.f;
        for (int p = 0; p < NPART; ++p) a += pb[(size_t)p * PREC2 + 16 + h * DIM + t];
        grow[t] = a;
        if (t < NPART) lp[t] = pb[(size_t)t * PREC2 + h];
        __syncthreads();
        if (t == 0) {
            float s = 0.f;
            #pragma unroll
            for (int p = 0; p < NPART; ++p) s += lp[p];
            *lsum = s;
        }
        __syncthreads();
        int i = h * 16 + (t >> 4), sub = t & 15;
        const float4* wrow = (const float4*)(Wv + (size_t)i * DIM + sub * 16);
        const float4* gr = (const float4*)(grow + sub * 16);
        float s = 0.f;
        #pragma unroll
        for (int k = 0; k < 4; ++k) {
            float4 wv = wrow[k], gv = gr[k];
            s += wv.x * gv.x + wv.y * gv.y + wv.z * gv.z + wv.w * gv.w;
        }
        s += __shfl_xor(s, 1, 64);
        s += __shfl_xor(s, 2, 64);
        s += __shfl_xor(s, 4, 64);
        s += __shfl_xor(s, 8, 64);
        if (sub == 0) hcws[(size_t)b * DIM + i] = s / *lsum;
    }
    __threadfence();
    grid.sync();

    if (bid < NB * 8) {
        int b = bid >> 3, o = bid & 7;
        int e = o * 32 + (t >> 3), sub = t & 7;
        const float4* wrow = (const float4*)(Wo + (size_t)e * DIM + sub * 32);
        const float4* hrow = (const float4*)(hcws + (size_t)b * DIM + sub * 32);
        float a = 0.f;
        #pragma unroll
        for (int k = 0; k < 8; ++k) {
            float4 wv = wrow[k], hv = hrow[k];
            a += wv.x * hv.x + wv.y * hv.y + wv.z * hv.z + wv.w * hv.w;
        }
        a += __shfl_xor(a, 1, 64);
        a += __shfl_xor(a, 2, 64);
        a += __shfl_xor(a, 4, 64);
        if (sub == 0) out[(size_t)b * DIM + e] = a;
    }
}

// ---------------- fallback kernels (round-16 proven path) -------------------
__global__ void prep_compact_kernel(const float* __restrict__ ctx,
                                    const float* __restrict__ Wq,
                                    const float* __restrict__ Wk,
                                    const void* __restrict__ maskp,
                                    float* __restrict__ wt,
                                    int* __restrict__ idx,
                                    int* __restrict__ cntp) {
    __shared__ __align__(16) char smem[1312];
    int bid = blockIdx.x;
    int t = threadIdx.x, lane = t & 63;
    if (bid < 4 * NB) {
        PREP_BODY(bid)
    } else {
        COMPACT_BODY(bid - 4 * NB)
    }
}

__launch_bounds__(256, 2)
__global__ void attend_kernel(const float* __restrict__ node,
                              const int* __restrict__ idx,
                              const int* __restrict__ cntp,
                              const float* __restrict__ wt,
                              float* __restrict__ partials) {
    __shared__ __align__(16) char smem[70400];
    int t = threadIdx.x, lane = t & 63;
    ATTEND_BODY(blockIdx.x)
}

__global__ void reduce_hc_kernel(const float* __restrict__ partials,
                                 const float* __restrict__ Wv,
                                 float* __restrict__ hcws) {
    int b = blockIdx.x >> 4, h = blockIdx.x & 15;
    int t = threadIdx.x;
    __shared__ float grow[DIM];
    __shared__ float lp[NPART];
    __shared__ float lsum;
    const float* pb = partials + (size_t)b * NPART * PREC2;
    float a = 0.f;
    for (int p = 0; p < NPART; ++p) a += pb[(size_t)p * PREC2 + 16 + h * DIM + t];
    grow[t] = a;
    if (t < NPART) lp[t] = pb[(size_t)t * PREC2 + h];
    __syncthreads();
    if (t == 0) {
        float s = 0.f;
        #pragma unroll
        for (int p = 0; p < NPART; ++p) s += lp[p];
        lsum = s;
    }
    __syncthreads();
    int i = h * 16 + (t >> 4), sub = t & 15;
    const float4* wrow = (const float4*)(Wv + (size_t)i * DIM + sub * 16);
    const float4* gr = (const float4*)(grow + sub * 16);
    float s = 0.f;
    #pragma unroll
    for (int k = 0; k < 4; ++k) {
        float4 wv = wrow[k], gv = gr[k];
        s += wv.x * gv.x + wv.y * gv.y + wv.z * gv.z + wv.w * gv.w;
    }
    s += __shfl_xor(s, 1, 64);
    s += __shfl_xor(s, 2, 64);
    s += __shfl_xor(s, 4, 64);
    s += __shfl_xor(s, 8, 64);
    if (sub == 0) hcws[(size_t)b * DIM + i] = s / lsum;
}

__global__ void out_kernel(const float* __restrict__ hcws,
                           const float* __restrict__ Wo,
                           float* __restrict__ out) {
    int b = blockIdx.x >> 3, o = blockIdx.x & 7;
    int t = threadIdx.x;
    int e = o * 32 + (t >> 3), sub = t & 7;
    const float4* wrow = (const float4*)(Wo + (size_t)e * DIM + sub * 32);
    const float4* hrow = (const float4*)(hcws + (size_t)b * DIM + sub * 32);
    float a = 0.f;
    #pragma unroll
    for (int k = 0; k < 8; ++k) {
        float4 wv = wrow[k], hv = hrow[k];
        a += wv.x * hv.x + wv.y * hv.y + wv.z * hv.z + wv.w * hv.w;
    }
    a += __shfl_xor(a, 1, 64);
    a += __shfl_xor(a, 2, 64);
    a += __shfl_xor(a, 4, 64);
    if (sub == 0) out[(size_t)b * DIM + e] = a;
}

extern "C" void kernel_launch(void* const* d_in, const int* in_sizes, int n_in,
                              void* d_out, int out_size, void* d_ws, size_t ws_size,
                              hipStream_t stream) {
    const float* ctx  = (const float*)d_in[0];
    const float* node = (const float*)d_in[1];
    const void*  mask = (const void*)d_in[2];
    const float* Wq   = (const float*)d_in[3];
    const float* Wk   = (const float*)d_in[4];
    const float* Wv   = (const float*)d_in[5];
    const float* Wo   = (const float*)d_in[6];
    float* out = (float*)d_out;

    float* wsf = (float*)d_ws;
    float* wt = wsf;
    float* hcws = wt + (size_t)NB * NH * DIM;
    int*   cnt = (int*)(hcws + (size_t)NB * DIM);
    int*   idx = cnt + 256;
    float* partials = (float*)(idx + (size_t)NB * IDXSTRIDE);

    // Deterministic, capture-safe path decision: host-side queries only.
    int dev = 0;
    hipGetDevice(&dev);
    int coopAttr = 0, ncu = 0, nb = 0;
    hipDeviceGetAttribute(&coopAttr, hipDeviceAttributeCooperativeLaunch, dev);
    hipDeviceGetAttribute(&ncu, hipDeviceAttributeMultiprocessorCount, dev);
    hipOccupancyMaxActiveBlocksPerMultiprocessor(&nb, (const void*)mega_kernel, 256, 0);

    if (coopAttr && (long)nb * ncu >= NB * NPART) {
        void* args[] = { (void*)&ctx, (void*)&node, (void*)&mask,
                         (void*)&Wq, (void*)&Wk, (void*)&Wv, (void*)&Wo,
                         (void*)&wt, (void*)&idx, (void*)&cnt,
                         (void*)&partials, (void*)&hcws, (void*)&out };
        hipError_t e = hipLaunchCooperativeKernel((const void*)mega_kernel,
                                                  dim3(NB * NPART), dim3(256),
                                                  args, 0, stream);
        if (e == hipSuccess) return;
        // fall through (should only happen outside capture if queries lied)
    }

    prep_compact_kernel<<<NB * 4 + NB, 256, 0, stream>>>(ctx, Wq, Wk, mask, wt, idx, cnt);
    attend_kernel<<<NB * NPART, 256, 0, stream>>>(node, idx, cnt, wt, partials);
    reduce_hc_kernel<<<NB * 16, 256, 0, stream>>>(partials, Wv, hcws);
    out_kernel<<<NB * 8, 256, 0, stream>>>(hcws, Wo, out);
}